// Round 6
// baseline (213.908 us; speedup 1.0000x reference)
//
#include <hip/hip_runtime.h>
#include <stdint.h>

// Flash attention fwd, B=16, L=2048, D=128, fp32 in/out.
// R6: 8-wave wgs (512 thr, 256 q-rows), kv-split x4, grid 512 -> 2 wgs/CU
// = 16 waves/CU (4/SIMD) for latency hiding. Prepass: K -> bf16 swizzled
// rows (unchanged), V -> bf16 V^T tiles now fully vectorized (register
// transpose + b128 LDS round-trip, no scalar reads). combine4 merges 4
// partials. Fallback if ws < 50.9 MB: R5 path (attn_split x2 + combine2).

typedef short bf16x8 __attribute__((ext_vector_type(8)));
typedef float f32x4 __attribute__((ext_vector_type(4)));
typedef unsigned int u32;
typedef unsigned short u16;

#define L_SEQ  2048
#define D_HEAD 128
#define TSZ    8388608u                    // bytes per bf16 tensor
// R6 layout: kb[TSZ] vt[TSZ] part[512*65536] lsum[512*256*4]
#define W2_PART (2u * TSZ)
#define W2_LSUM (W2_PART + 512u * 65536u)
#define WS_NEED2 (W2_LSUM + 512u * 256u * 4u)    // 50,855,936
// R5 layout: kb[TSZ] vt[TSZ] part5[512*32768] lsum5[512*128*4]
#define W5_PART (2u * TSZ)
#define W5_LSUM (W5_PART + 512u * 32768u)
#define WS_NEED5 (W5_LSUM + 512u * 128u * 4u)    // 33,816,576

__device__ __forceinline__ unsigned pk2(float lo, float hi) {
    union { float f; unsigned u; } a, b;
    a.f = lo; b.f = hi;
    return __builtin_amdgcn_perm(b.u + 0x8000u, a.u + 0x8000u, 0x07060302u);
}
__device__ __forceinline__ float ex2(float x) { return __builtin_amdgcn_exp2f(x); }
__device__ __forceinline__ float bflo(unsigned w) {
    union { unsigned u; float f; } v; v.u = w << 16; return v.f;
}
__device__ __forceinline__ float bfhi(unsigned w) {
    union { unsigned u; float f; } v; v.u = w & 0xffff0000u; return v.f;
}
__device__ __forceinline__ void gl_lds16(const u16* g, u16* l) {
    __builtin_amdgcn_global_load_lds(
        (const __attribute__((address_space(1))) u32*)g,
        (__attribute__((address_space(3))) u32*)l, 16, 0, 0);
}

// ---------------- pre-pass -------------------------------------------------
// wg 0..511:  K -> bf16 rows, granule swizzle gp_stored = gp_logical^(row&7)
// wg 512..1023: V -> V^T bf16 tiles [tile][d=128][8 gp swz][8 kv], vectorized
__global__ __launch_bounds__(256, 4)
void prepass(const float* __restrict__ K, const float* __restrict__ V,
             u16* __restrict__ kb, u16* __restrict__ vt) {
    const int id = blockIdx.x, t = threadIdx.x;
    if (id < 512) {
        const float* src = K + (size_t)id * 64 * 128;
        u16*        dst = kb + (size_t)id * 64 * 128;
        const int r = t >> 2;
        #pragma unroll
        for (int i = 0; i < 4; ++i) {
            int gp = (t & 3) * 4 + i;
            int gs = gp ^ (r & 7);
            const float* s = src + r * 128 + gs * 8;
            float4 x0 = *(const float4*)s, x1 = *(const float4*)(s + 4);
            uint4 w;
            w.x = pk2(x0.x, x0.y); w.y = pk2(x0.z, x0.w);
            w.z = pk2(x1.x, x1.y); w.w = pk2(x1.z, x1.w);
            *(uint4*)(dst + r * 128 + gp * 8) = w;
        }
    } else {
        // V^T: phase 1 = register 8x4 transpose -> LDS V^T rows (b128 writes)
        __shared__ __align__(16) u16 vl[128 * 72];
        const int bid = id - 512;
        const float* src = V + (size_t)bid * 64 * 128;
        const int vcc = t & 31, vgk = t >> 5;   // d 4-chunk, kv 8-group
        union { float4 v; float f[4]; } vr[8];
        const float* vp = src + (size_t)(vgk * 8) * 128 + vcc * 4;
        #pragma unroll
        for (int r = 0; r < 8; ++r) vr[r].v = *(const float4*)(vp + (size_t)r * 128);
        #pragma unroll
        for (int dd = 0; dd < 4; ++dd) {
            uint4 w;
            w.x = pk2(vr[0].f[dd], vr[1].f[dd]);
            w.y = pk2(vr[2].f[dd], vr[3].f[dd]);
            w.z = pk2(vr[4].f[dd], vr[5].f[dd]);
            w.w = pk2(vr[6].f[dd], vr[7].f[dd]);
            *(uint4*)(&vl[(vcc * 4 + dd) * 72 + vgk * 8]) = w;
        }
        __syncthreads();
        // phase 2: b128 swizzled reads (uniform windows), coalesced stores
        u16* dst = vt + (size_t)bid * 8192;
        #pragma unroll
        for (int i = 0; i < 4; ++i) {
            int flat = t + 256 * i;
            int d = flat >> 3, gp = flat & 7;
            uint4 w = *(const uint4*)(&vl[d * 72 + ((gp ^ (d & 7)) * 8)]);
            *(uint4*)(dst + (size_t)flat * 8) = w;
        }
    }
}

// ---------------- R6 main kernel: 8 waves, 256 q-rows, kv quarter ----------
// LDS: Kbuf 0..16K, Vbuf 16K..32K, P 32K..68K (8 waves x 32 x 72 u16)
__global__ __launch_bounds__(512, 4)
void attn8(const float* __restrict__ Qg, const u16* __restrict__ kb,
           const u16* __restrict__ vt, u16* __restrict__ part,
           float* __restrict__ lsum) {
    __shared__ __align__(16) char smem[69632];
    const int tid = threadIdx.x;
    const int wv = tid >> 6, lane = tid & 63;
    const int c = lane & 15, qd = lane >> 4, cx = c & 7;
    const int bid = blockIdx.x;
    const int p = bid >> 2, kvh = bid & 3;
    const int b = p & 15, qblk = p >> 4;      // qblk in [0,8)

    const float* Qp = Qg + (size_t)b * L_SEQ * D_HEAD;
    const u16*   Kp = kb + (size_t)b * L_SEQ * D_HEAD + (size_t)kvh * 512 * 128;
    const u16*   Vp = vt + (size_t)b * 32 * 8192 + (size_t)kvh * 8 * 8192;
    u16* Kl = (u16*)smem;
    u16* Vl = (u16*)(smem + 16384);
    u16* Pl = (u16*)(smem + 32768) + wv * 2304;

    const int so = tid * 8;   // u16 units; 512 thr x 16B x 2 = 16 KB tile

    #pragma unroll
    for (int i = 0; i < 2; ++i) {
        gl_lds16(Kp + so + i * 4096, Kl + so + i * 4096);
        gl_lds16(Vp + so + i * 4096, Vl + so + i * 4096);
    }

    const float QS = 1.4426950408889634f / 11.313708498984761f; // log2e/sqrt(128)
    bf16x8 qf[2][4];
    #pragma unroll
    for (int s = 0; s < 2; ++s) {
        const float* qrow = Qp + (size_t)(qblk * 256 + wv * 32 + s * 16 + c) * 128 + qd * 8;
        #pragma unroll
        for (int kt = 0; kt < 4; ++kt) {
            float4 x0 = *(const float4*)(qrow + kt * 32);
            float4 x1 = *(const float4*)(qrow + kt * 32 + 4);
            union { unsigned u[4]; bf16x8 v; } tt;
            tt.u[0] = pk2(x0.x * QS, x0.y * QS);
            tt.u[1] = pk2(x0.z * QS, x0.w * QS);
            tt.u[2] = pk2(x1.x * QS, x1.y * QS);
            tt.u[3] = pk2(x1.z * QS, x1.w * QS);
            qf[s][kt] = tt.v;
        }
    }

    f32x4 acc[2][8];
    #pragma unroll
    for (int s = 0; s < 2; ++s)
        #pragma unroll
        for (int dt = 0; dt < 8; ++dt) acc[s][dt] = (f32x4){0.f, 0.f, 0.f, 0.f};
    float lrun[2] = {0.f, 0.f};

    __syncthreads();   // tile 0 arrived

    for (int it = 0; it < 8; ++it) {
        // ---- S^T = K.Q^T
        f32x4 st[4][2];
        #pragma unroll
        for (int v = 0; v < 4; ++v) {
            st[v][0] = (f32x4){0.f, 0.f, 0.f, 0.f};
            st[v][1] = (f32x4){0.f, 0.f, 0.f, 0.f};
        }
        #pragma unroll
        for (int kt = 0; kt < 4; ++kt) {
            const int g = ((kt * 4 + qd) ^ cx) * 8;
            #pragma unroll
            for (int v = 0; v < 4; ++v) {
                bf16x8 a = *(const bf16x8*)(Kl + (v * 16 + c) * 128 + g);
                st[v][0] = __builtin_amdgcn_mfma_f32_16x16x32_bf16(a, qf[0][kt], st[v][0], 0, 0, 0);
                st[v][1] = __builtin_amdgcn_mfma_f32_16x16x32_bf16(a, qf[1][kt], st[v][1], 0, 0, 0);
            }
        }
        __syncthreads();   // barrier 1: V(it) DMA drained; K-reads done

        if (it + 1 < 8) {
            const u16* kg = Kp + (size_t)(it + 1) * 8192 + so;
            #pragma unroll
            for (int i = 0; i < 2; ++i) gl_lds16(kg + i * 4096, Kl + so + i * 4096);
        }

        // ---- sum-only softmax + per-wave P round-trip
        #pragma unroll
        for (int s = 0; s < 2; ++s) {
            float lsm = 0.f;
            #pragma unroll
            for (int v = 0; v < 4; ++v) {
                float p0 = ex2(st[v][s].x), p1 = ex2(st[v][s].y);
                float p2 = ex2(st[v][s].z), p3 = ex2(st[v][s].w);
                lsm += (p0 + p1) + (p2 + p3);
                uint2 w; w.x = pk2(p0, p1); w.y = pk2(p2, p3);
                *(uint2*)(Pl + (s * 16 + c) * 72 + v * 16 + qd * 4) = w;
            }
            lrun[s] += lsm;
        }
        bf16x8 pf[2][2];
        #pragma unroll
        for (int h = 0; h < 2; ++h)
            #pragma unroll
            for (int s = 0; s < 2; ++s)
                pf[h][s] = *(const bf16x8*)(Pl + (s * 16 + c) * 72 + h * 32 + qd * 8);

        // ---- O^T += V^T.P^T
        #pragma unroll
        for (int dt = 0; dt < 8; ++dt) {
            #pragma unroll
            for (int h = 0; h < 2; ++h) {
                bf16x8 a = *(const bf16x8*)(Vl + (dt * 16 + c) * 64 + ((h * 4 + qd) ^ cx) * 8);
                acc[0][dt] = __builtin_amdgcn_mfma_f32_16x16x32_bf16(a, pf[h][0], acc[0][dt], 0, 0, 0);
                acc[1][dt] = __builtin_amdgcn_mfma_f32_16x16x32_bf16(a, pf[h][1], acc[1][dt], 0, 0, 0);
            }
        }
        __syncthreads();   // barrier 2: K(it+1) DMA drained; V-reads done

        if (it + 1 < 8) {
            const u16* vg = Vp + (size_t)(it + 1) * 8192 + so;
            #pragma unroll
            for (int i = 0; i < 2; ++i) gl_lds16(vg + i * 4096, Vl + so + i * 4096);
        }
    }

    // ---- epilogue: reduce l, write bf16 O^T-partial + l
    float ls[2];
    #pragma unroll
    for (int s = 0; s < 2; ++s) {
        float l = lrun[s];
        l += __shfl_xor(l, 16);
        l += __shfl_xor(l, 32);
        ls[s] = l;
    }
    u16* pb = part + (size_t)bid * 32768;   // 64 KB per wg
    #pragma unroll
    for (int s = 0; s < 2; ++s)
        #pragma unroll
        for (int dt = 0; dt < 8; ++dt) {
            f32x4 o = acc[s][dt];
            uint2 w; w.x = pk2(o.x, o.y); w.y = pk2(o.z, o.w);
            *(uint2*)(pb + ((((wv * 2 + s) * 8 + dt) * 64 + lane) << 2)) = w;
        }
    if (qd == 0) {
        int base = p * 1024 + kvh * 256 + wv * 32;
        lsum[base + c]      = ls[0];
        lsum[base + 16 + c] = ls[1];
    }
}

// ---------------- combine4: O = (sum Ok)/(sum lk), transpose, store --------
__global__ __launch_bounds__(256, 2)
void combine4(const u16* __restrict__ part, const float* __restrict__ lsum,
              float* __restrict__ Og) {
    __shared__ float inv[256];
    __shared__ __align__(16) float Ol[64 * 132];
    const int t = threadIdx.x, p = blockIdx.x;   // p in [0,128)
    const int b = p & 15, qblk = p >> 4;
    {
        const float* lp = lsum + p * 1024;
        inv[t] = 1.0f / (lp[t] + lp[256 + t] + lp[512 + t] + lp[768 + t]);
    }
    const uint2* P0 = (const uint2*)(part + (size_t)(4 * p + 0) * 32768);
    const uint2* P1 = (const uint2*)(part + (size_t)(4 * p + 1) * 32768);
    const uint2* P2 = (const uint2*)(part + (size_t)(4 * p + 2) * 32768);
    const uint2* P3 = (const uint2*)(part + (size_t)(4 * p + 3) * 32768);
    __syncthreads();
    #pragma unroll
    for (int h = 0; h < 4; ++h) {
        #pragma unroll
        for (int i = 0; i < 8; ++i) {
            int slot = i * 256 + t;
            int lc = slot >> 6, lane = slot & 63;
            int gc = h * 32 + lc;
            int s = (gc >> 3) & 1, dt = gc & 7;
            int qd = lane >> 4, c = lane & 15;
            int row = (lc >> 4) * 32 + s * 16 + c;   // q within 64-row pass
            int d0 = dt * 16 + qd * 4;
            size_t idx = (size_t)gc * 64 + lane;
            uint2 w0 = P0[idx], w1 = P1[idx], w2 = P2[idx], w3 = P3[idx];
            float iv = inv[h * 64 + row];
            float4 o;
            o.x = (bflo(w0.x) + bflo(w1.x) + bflo(w2.x) + bflo(w3.x)) * iv;
            o.y = (bfhi(w0.x) + bfhi(w1.x) + bfhi(w2.x) + bfhi(w3.x)) * iv;
            o.z = (bflo(w0.y) + bflo(w1.y) + bflo(w2.y) + bflo(w3.y)) * iv;
            o.w = (bfhi(w0.y) + bfhi(w1.y) + bfhi(w2.y) + bfhi(w3.y)) * iv;
            *(float4*)(&Ol[row * 132 + d0]) = o;
        }
        __syncthreads();
        #pragma unroll
        for (int i = 0; i < 8; ++i) {
            int slot = i * 256 + t;
            int row = slot >> 5, c4 = slot & 31;
            float4 val = *(const float4*)(&Ol[row * 132 + c4 * 4]);
            size_t q = (size_t)b * L_SEQ + qblk * 256 + h * 64 + row;
            *(float4*)(Og + q * D_HEAD + c4 * 4) = val;
        }
        __syncthreads();
    }
}

// ---------------- R5 fallback path (proven, ws >= 33.8 MB) -----------------
__global__ __launch_bounds__(256, 2)
void attn_split(const float* __restrict__ Qg, const u16* __restrict__ kb,
                const u16* __restrict__ vt, u16* __restrict__ part,
                float* __restrict__ lsum) {
    __shared__ __align__(16) char smem[51200];
    const int tid = threadIdx.x;
    const int wv = tid >> 6, lane = tid & 63;
    const int c = lane & 15, qd = lane >> 4, cx = c & 7;
    const int bid = blockIdx.x;
    const int p = bid >> 1, kvh = bid & 1;
    const int b = p & 15, qblk = p >> 4;

    const float* Qp = Qg + (size_t)b * L_SEQ * D_HEAD;
    const u16*   Kp = kb + (size_t)b * L_SEQ * D_HEAD + (size_t)kvh * 1024 * 128;
    const u16*   Vp = vt + (size_t)b * 32 * 8192 + (size_t)kvh * 16 * 8192;
    u16* Kl = (u16*)smem;
    u16* Vl = (u16*)(smem + 16384);
    u16* Pl = (u16*)(smem + 32768) + wv * 2304;

    const int so = wv * 2048 + lane * 8;

    #pragma unroll
    for (int i = 0; i < 4; ++i) {
        gl_lds16(Kp + so + i * 512, Kl + so + i * 512);
        gl_lds16(Vp + so + i * 512, Vl + so + i * 512);
    }

    const float QS = 1.4426950408889634f / 11.313708498984761f;
    bf16x8 qf[2][4];
    #pragma unroll
    for (int s = 0; s < 2; ++s) {
        const float* qrow = Qp + (size_t)(qblk * 128 + wv * 32 + s * 16 + c) * 128 + qd * 8;
        #pragma unroll
        for (int kt = 0; kt < 4; ++kt) {
            float4 x0 = *(const float4*)(qrow + kt * 32);
            float4 x1 = *(const float4*)(qrow + kt * 32 + 4);
            union { unsigned u[4]; bf16x8 v; } tt;
            tt.u[0] = pk2(x0.x * QS, x0.y * QS);
            tt.u[1] = pk2(x0.z * QS, x0.w * QS);
            tt.u[2] = pk2(x1.x * QS, x1.y * QS);
            tt.u[3] = pk2(x1.z * QS, x1.w * QS);
            qf[s][kt] = tt.v;
        }
    }

    f32x4 acc[2][8];
    #pragma unroll
    for (int s = 0; s < 2; ++s)
        #pragma unroll
        for (int dt = 0; dt < 8; ++dt) acc[s][dt] = (f32x4){0.f, 0.f, 0.f, 0.f};
    float lrun[2] = {0.f, 0.f};

    __syncthreads();

    for (int it = 0; it < 16; ++it) {
        f32x4 st[4][2];
        #pragma unroll
        for (int v = 0; v < 4; ++v) {
            st[v][0] = (f32x4){0.f, 0.f, 0.f, 0.f};
            st[v][1] = (f32x4){0.f, 0.f, 0.f, 0.f};
        }
        #pragma unroll
        for (int kt = 0; kt < 4; ++kt) {
            const int g = ((kt * 4 + qd) ^ cx) * 8;
            #pragma unroll
            for (int v = 0; v < 4; ++v) {
                bf16x8 a = *(const bf16x8*)(Kl + (v * 16 + c) * 128 + g);
                st[v][0] = __builtin_amdgcn_mfma_f32_16x16x32_bf16(a, qf[0][kt], st[v][0], 0, 0, 0);
                st[v][1] = __builtin_amdgcn_mfma_f32_16x16x32_bf16(a, qf[1][kt], st[v][1], 0, 0, 0);
            }
        }
        __syncthreads();

        if (it + 1 < 16) {
            const u16* kg = Kp + (size_t)(it + 1) * 8192 + so;
            #pragma unroll
            for (int i = 0; i < 4; ++i) gl_lds16(kg + i * 512, Kl + so + i * 512);
        }

        #pragma unroll
        for (int s = 0; s < 2; ++s) {
            float lsm = 0.f;
            #pragma unroll
            for (int v = 0; v < 4; ++v) {
                float p0 = ex2(st[v][s].x), p1 = ex2(st[v][s].y);
                float p2 = ex2(st[v][s].z), p3 = ex2(st[v][s].w);
                lsm += (p0 + p1) + (p2 + p3);
                uint2 w; w.x = pk2(p0, p1); w.y = pk2(p2, p3);
                *(uint2*)(Pl + (s * 16 + c) * 72 + v * 16 + qd * 4) = w;
            }
            lrun[s] += lsm;
        }
        bf16x8 pf[2][2];
        #pragma unroll
        for (int h = 0; h < 2; ++h)
            #pragma unroll
            for (int s = 0; s < 2; ++s)
                pf[h][s] = *(const bf16x8*)(Pl + (s * 16 + c) * 72 + h * 32 + qd * 8);

        #pragma unroll
        for (int dt = 0; dt < 8; ++dt) {
            #pragma unroll
            for (int h = 0; h < 2; ++h) {
                bf16x8 a = *(const bf16x8*)(Vl + (dt * 16 + c) * 64 + ((h * 4 + qd) ^ cx) * 8);
                acc[0][dt] = __builtin_amdgcn_mfma_f32_16x16x32_bf16(a, pf[h][0], acc[0][dt], 0, 0, 0);
                acc[1][dt] = __builtin_amdgcn_mfma_f32_16x16x32_bf16(a, pf[h][1], acc[1][dt], 0, 0, 0);
            }
        }
        __syncthreads();

        if (it + 1 < 16) {
            const u16* vg = Vp + (size_t)(it + 1) * 8192 + so;
            #pragma unroll
            for (int i = 0; i < 4; ++i) gl_lds16(vg + i * 512, Vl + so + i * 512);
        }
    }

    float ls[2];
    #pragma unroll
    for (int s = 0; s < 2; ++s) {
        float l = lrun[s];
        l += __shfl_xor(l, 16);
        l += __shfl_xor(l, 32);
        ls[s] = l;
    }
    u16* pb = part + (size_t)bid * 16384;
    #pragma unroll
    for (int s = 0; s < 2; ++s)
        #pragma unroll
        for (int dt = 0; dt < 8; ++dt) {
            f32x4 o = acc[s][dt];
            uint2 w; w.x = pk2(o.x, o.y); w.y = pk2(o.z, o.w);
            *(uint2*)(pb + ((((wv * 2 + s) * 8 + dt) * 64 + lane) << 2)) = w;
        }
    if (qd == 0) {
        lsum[p * 256 + kvh * 128 + wv * 32 + c]      = ls[0];
        lsum[p * 256 + kvh * 128 + wv * 32 + 16 + c] = ls[1];
    }
}

__global__ __launch_bounds__(256, 2)
void combine2(const u16* __restrict__ part, const float* __restrict__ lsum,
              float* __restrict__ Og) {
    __shared__ float inv[128];
    __shared__ __align__(16) float Ol[64 * 132];
    const int t = threadIdx.x, p = blockIdx.x;
    const int b = p & 15, qblk = p >> 4;
    if (t < 128) {
        float la = lsum[p * 256 + t], lb = lsum[p * 256 + 128 + t];
        inv[t] = 1.0f / (la + lb);
    }
    const uint2* A = (const uint2*)(part + (size_t)(2 * p) * 16384);
    const uint2* B = (const uint2*)(part + (size_t)(2 * p + 1) * 16384);
    __syncthreads();
    #pragma unroll
    for (int h = 0; h < 2; ++h) {
        #pragma unroll
        for (int i = 0; i < 8; ++i) {
            int slot = i * 256 + t;
            int lc = slot >> 6, lane = slot & 63;
            int gc = h * 32 + lc;
            int s = (lc >> 3) & 1, dt = lc & 7;
            int qd = lane >> 4, c = lane & 15;
            int row = (lc >> 4) * 32 + s * 16 + c;
            int d0 = dt * 16 + qd * 4;
            uint2 wa = A[(size_t)gc * 64 + lane];
            uint2 wb = B[(size_t)gc * 64 + lane];
            float iv = inv[h * 64 + row];
            float4 o;
            o.x = (bflo(wa.x) + bflo(wb.x)) * iv;
            o.y = (bfhi(wa.x) + bfhi(wb.x)) * iv;
            o.z = (bflo(wa.y) + bflo(wb.y)) * iv;
            o.w = (bfhi(wa.y) + bfhi(wb.y)) * iv;
            *(float4*)(&Ol[row * 132 + d0]) = o;
        }
        __syncthreads();
        #pragma unroll
        for (int i = 0; i < 8; ++i) {
            int slot = i * 256 + t;
            int row = slot >> 5, c4 = slot & 31;
            float4 val = *(const float4*)(&Ol[row * 132 + c4 * 4]);
            size_t q = (size_t)b * L_SEQ + qblk * 128 + h * 64 + row;
            *(float4*)(Og + q * D_HEAD + c4 * 4) = val;
        }
        __syncthreads();
    }
}

extern "C" void kernel_launch(void* const* d_in, const int* in_sizes, int n_in,
                              void* d_out, int out_size, void* d_ws, size_t ws_size,
                              hipStream_t stream) {
    const float* q = (const float*)d_in[0];
    const float* k = (const float*)d_in[1];
    const float* v = (const float*)d_in[2];
    float* out = (float*)d_out;
    u16* kb = (u16*)d_ws;
    u16* vt = (u16*)((char*)d_ws + TSZ);
    prepass<<<dim3(1024), dim3(256), 0, stream>>>(k, v, kb, vt);
    if (ws_size >= (size_t)WS_NEED2) {
        u16* part = (u16*)((char*)d_ws + W2_PART);
        float* ls = (float*)((char*)d_ws + W2_LSUM);
        attn8<<<dim3(512), dim3(512), 0, stream>>>(q, kb, vt, part, ls);
        combine4<<<dim3(128), dim3(256), 0, stream>>>(part, ls, out);
    } else {
        u16* part = (u16*)((char*)d_ws + W5_PART);
        float* ls = (float*)((char*)d_ws + W5_LSUM);
        attn_split<<<dim3(512), dim3(256), 0, stream>>>(q, kb, vt, part, ls);
        combine2<<<dim3(256), dim3(256), 0, stream>>>(part, ls, out);
    }
}

// Round 7
// 139.876 us; speedup vs baseline: 1.5293x; 1.5293x over previous
//
#include <hip/hip_runtime.h>
#include <stdint.h>

// Flash attention fwd, B=16, L=2048, D=128, fp32 in/out.
// R7: R5's proven 256-thread kernel + kv-split x3 (grid 768 = 3 wgs/CU,
// 12 waves/CU) + P-buffer swizzled to stride 64 (LDS 48 KB so 3 wgs fit).
// prepass: K -> bf16 swizzled rows, V -> bf16 V^T tiles (vectorized).
// attn3: global_load_lds staging, split-barrier, 16x16x32 bf16 MFMA,
// sum-only exp2 softmax, bf16 O^T partials + l partials to ws.
// combine3: O = (O0+O1+O2)/(l0+l1+l2), transpose via LDS, store.

typedef short bf16x8 __attribute__((ext_vector_type(8)));
typedef float f32x4 __attribute__((ext_vector_type(4)));
typedef unsigned int u32;
typedef unsigned short u16;

#define L_SEQ  2048
#define D_HEAD 128
#define TSZ    8388608u                          // bytes per bf16 tensor
#define W_PART (2u * TSZ)                        // 768 x 32 KB partials
#define W_LSUM (W_PART + 768u * 32768u)
#define WS_NEED (W_LSUM + 768u * 128u * 4u)      // 42,336,256 B

__device__ __forceinline__ unsigned pk2(float lo, float hi) {
    union { float f; unsigned u; } a, b;
    a.f = lo; b.f = hi;
    return __builtin_amdgcn_perm(b.u + 0x8000u, a.u + 0x8000u, 0x07060302u);
}
__device__ __forceinline__ float ex2(float x) { return __builtin_amdgcn_exp2f(x); }
__device__ __forceinline__ float bflo(unsigned w) {
    union { unsigned u; float f; } v; v.u = w << 16; return v.f;
}
__device__ __forceinline__ float bfhi(unsigned w) {
    union { unsigned u; float f; } v; v.u = w & 0xffff0000u; return v.f;
}
__device__ __forceinline__ void gl_lds16(const u16* g, u16* l) {
    __builtin_amdgcn_global_load_lds(
        (const __attribute__((address_space(1))) u32*)g,
        (__attribute__((address_space(3))) u32*)l, 16, 0, 0);
}

// ---------------- pre-pass -------------------------------------------------
// wg 0..511:  K -> bf16 rows, granule swizzle gp_stored = gp_logical^(row&7)
// wg 512..1023: V -> V^T bf16 tiles [tile][d=128][8 gp swz][8 kv], vectorized
__global__ __launch_bounds__(256, 4)
void prepass(const float* __restrict__ K, const float* __restrict__ V,
             u16* __restrict__ kb, u16* __restrict__ vt) {
    const int id = blockIdx.x, t = threadIdx.x;
    if (id < 512) {
        const float* src = K + (size_t)id * 64 * 128;
        u16*        dst = kb + (size_t)id * 64 * 128;
        const int r = t >> 2;
        #pragma unroll
        for (int i = 0; i < 4; ++i) {
            int gp = (t & 3) * 4 + i;
            int gs = gp ^ (r & 7);
            const float* s = src + r * 128 + gs * 8;
            float4 x0 = *(const float4*)s, x1 = *(const float4*)(s + 4);
            uint4 w;
            w.x = pk2(x0.x, x0.y); w.y = pk2(x0.z, x0.w);
            w.z = pk2(x1.x, x1.y); w.w = pk2(x1.z, x1.w);
            *(uint4*)(dst + r * 128 + gp * 8) = w;
        }
    } else {
        // V^T: register 8x4 transpose -> LDS rows (b128) -> swizzled stores
        __shared__ __align__(16) u16 vl[128 * 72];
        const int bid = id - 512;
        const float* src = V + (size_t)bid * 64 * 128;
        const int vcc = t & 31, vgk = t >> 5;
        union { float4 v; float f[4]; } vr[8];
        const float* vp = src + (size_t)(vgk * 8) * 128 + vcc * 4;
        #pragma unroll
        for (int r = 0; r < 8; ++r) vr[r].v = *(const float4*)(vp + (size_t)r * 128);
        #pragma unroll
        for (int dd = 0; dd < 4; ++dd) {
            uint4 w;
            w.x = pk2(vr[0].f[dd], vr[1].f[dd]);
            w.y = pk2(vr[2].f[dd], vr[3].f[dd]);
            w.z = pk2(vr[4].f[dd], vr[5].f[dd]);
            w.w = pk2(vr[6].f[dd], vr[7].f[dd]);
            *(uint4*)(&vl[(vcc * 4 + dd) * 72 + vgk * 8]) = w;
        }
        __syncthreads();
        u16* dst = vt + (size_t)bid * 8192;
        #pragma unroll
        for (int i = 0; i < 4; ++i) {
            int flat = t + 256 * i;
            int d = flat >> 3, gp = flat & 7;
            uint4 w = *(const uint4*)(&vl[d * 72 + ((gp ^ (d & 7)) * 8)]);
            *(uint4*)(dst + (size_t)flat * 8) = w;
        }
    }
}

// ---------------- main kernel: kv third per wg -----------------------------
// LDS: Kbuf 0..16K, Vbuf 16K..32K, P 32K..48K (4 waves x 32 x 64 u16 swz)
__global__ __launch_bounds__(256, 2)
void attn3(const float* __restrict__ Qg, const u16* __restrict__ kb,
           const u16* __restrict__ vt, u16* __restrict__ part,
           float* __restrict__ lsum) {
    __shared__ __align__(16) char smem[49152];
    const int tid = threadIdx.x;
    const int wv = tid >> 6, lane = tid & 63;
    const int c = lane & 15, qd = lane >> 4, cx = c & 7;
    const int bid = blockIdx.x;
    const int p = bid & 255, kvh = bid >> 8;       // kvh in {0,1,2}
    const int b = p & 15, qblk = p >> 4;
    const int t0 = kvh * 11;                       // first 64-tile
    const int nt = (kvh < 2) ? 11 : 10;            // tiles this wg

    const float* Qp = Qg + (size_t)b * L_SEQ * D_HEAD;
    const u16*   Kp = kb + (size_t)b * L_SEQ * D_HEAD + (size_t)t0 * 8192;
    const u16*   Vp = vt + (size_t)b * 32 * 8192 + (size_t)t0 * 8192;
    u16* Kl = (u16*)smem;
    u16* Vl = (u16*)(smem + 16384);
    u16* Pl = (u16*)(smem + 32768) + wv * 2048;    // 32 rows x 64 u16, swizzled

    const int so = wv * 2048 + lane * 8;           // DMA offset, u16 units
    const int psw = (c & 7) << 1;                  // P granule swizzle constant

    #pragma unroll
    for (int i = 0; i < 4; ++i) {
        gl_lds16(Kp + so + i * 512, Kl + so + i * 512);
        gl_lds16(Vp + so + i * 512, Vl + so + i * 512);
    }

    const float QS = 1.4426950408889634f / 11.313708498984761f; // log2e/sqrt(128)
    bf16x8 qf[2][4];
    #pragma unroll
    for (int s = 0; s < 2; ++s) {
        const float* qrow = Qp + (size_t)(qblk * 128 + wv * 32 + s * 16 + c) * 128 + qd * 8;
        #pragma unroll
        for (int kt = 0; kt < 4; ++kt) {
            float4 x0 = *(const float4*)(qrow + kt * 32);
            float4 x1 = *(const float4*)(qrow + kt * 32 + 4);
            union { unsigned u[4]; bf16x8 v; } tt;
            tt.u[0] = pk2(x0.x * QS, x0.y * QS);
            tt.u[1] = pk2(x0.z * QS, x0.w * QS);
            tt.u[2] = pk2(x1.x * QS, x1.y * QS);
            tt.u[3] = pk2(x1.z * QS, x1.w * QS);
            qf[s][kt] = tt.v;
        }
    }

    f32x4 acc[2][8];
    #pragma unroll
    for (int s = 0; s < 2; ++s)
        #pragma unroll
        for (int dt = 0; dt < 8; ++dt) acc[s][dt] = (f32x4){0.f, 0.f, 0.f, 0.f};
    float lrun[2] = {0.f, 0.f};

    __syncthreads();   // tile 0 arrived

    for (int it = 0; it < nt; ++it) {
        // ---- S^T = K.Q^T
        f32x4 st[4][2];
        #pragma unroll
        for (int v = 0; v < 4; ++v) {
            st[v][0] = (f32x4){0.f, 0.f, 0.f, 0.f};
            st[v][1] = (f32x4){0.f, 0.f, 0.f, 0.f};
        }
        #pragma unroll
        for (int kt = 0; kt < 4; ++kt) {
            const int g = ((kt * 4 + qd) ^ cx) * 8;
            #pragma unroll
            for (int v = 0; v < 4; ++v) {
                bf16x8 a = *(const bf16x8*)(Kl + (v * 16 + c) * 128 + g);
                st[v][0] = __builtin_amdgcn_mfma_f32_16x16x32_bf16(a, qf[0][kt], st[v][0], 0, 0, 0);
                st[v][1] = __builtin_amdgcn_mfma_f32_16x16x32_bf16(a, qf[1][kt], st[v][1], 0, 0, 0);
            }
        }
        __syncthreads();   // barrier 1: V(it) DMA drained; K-reads done

        if (it + 1 < nt) {
            const u16* kg = Kp + (size_t)(it + 1) * 8192 + so;
            #pragma unroll
            for (int i = 0; i < 4; ++i) gl_lds16(kg + i * 512, Kl + so + i * 512);
        }

        // ---- sum-only softmax + per-wave swizzled P round-trip
        #pragma unroll
        for (int s = 0; s < 2; ++s) {
            float lsm = 0.f;
            #pragma unroll
            for (int v = 0; v < 4; ++v) {
                float p0 = ex2(st[v][s].x), p1 = ex2(st[v][s].y);
                float p2 = ex2(st[v][s].z), p3 = ex2(st[v][s].w);
                lsm += (p0 + p1) + (p2 + p3);
                uint2 w; w.x = pk2(p0, p1); w.y = pk2(p2, p3);
                int gsw = (v * 4 + qd) ^ psw;           // granule swizzle
                *(uint2*)(Pl + (s * 16 + c) * 64 + gsw * 4) = w;
            }
            lrun[s] += lsm;
        }
        bf16x8 pf[2][2];
        #pragma unroll
        for (int h = 0; h < 2; ++h) {
            int gsw = (h * 8 + qd * 2) ^ psw;           // even: b128 stays contiguous
            #pragma unroll
            for (int s = 0; s < 2; ++s)
                pf[h][s] = *(const bf16x8*)(Pl + (s * 16 + c) * 64 + gsw * 4);
        }

        // ---- O^T += V^T.P^T
        #pragma unroll
        for (int dt = 0; dt < 8; ++dt) {
            #pragma unroll
            for (int h = 0; h < 2; ++h) {
                bf16x8 a = *(const bf16x8*)(Vl + (dt * 16 + c) * 64 + ((h * 4 + qd) ^ cx) * 8);
                acc[0][dt] = __builtin_amdgcn_mfma_f32_16x16x32_bf16(a, pf[h][0], acc[0][dt], 0, 0, 0);
                acc[1][dt] = __builtin_amdgcn_mfma_f32_16x16x32_bf16(a, pf[h][1], acc[1][dt], 0, 0, 0);
            }
        }
        __syncthreads();   // barrier 2: K(it+1) DMA drained; V-reads done

        if (it + 1 < nt) {
            const u16* vg = Vp + (size_t)(it + 1) * 8192 + so;
            #pragma unroll
            for (int i = 0; i < 4; ++i) gl_lds16(vg + i * 512, Vl + so + i * 512);
        }
    }

    // ---- epilogue: reduce l, write bf16 O^T-partial + l
    float ls[2];
    #pragma unroll
    for (int s = 0; s < 2; ++s) {
        float l = lrun[s];
        l += __shfl_xor(l, 16);
        l += __shfl_xor(l, 32);
        ls[s] = l;
    }
    u16* pb = part + (size_t)bid * 16384;   // 32 KB per wg
    #pragma unroll
    for (int s = 0; s < 2; ++s)
        #pragma unroll
        for (int dt = 0; dt < 8; ++dt) {
            f32x4 o = acc[s][dt];
            uint2 w; w.x = pk2(o.x, o.y); w.y = pk2(o.z, o.w);
            *(uint2*)(pb + ((((wv * 2 + s) * 8 + dt) * 64 + lane) << 2)) = w;
        }
    if (qd == 0) {
        lsum[kvh * 32768 + p * 128 + wv * 32 + c]      = ls[0];
        lsum[kvh * 32768 + p * 128 + wv * 32 + 16 + c] = ls[1];
    }
}

// ---------------- combine3: O = (sum Ok)/(sum lk), transpose, store --------
__global__ __launch_bounds__(256, 2)
void combine3(const u16* __restrict__ part, const float* __restrict__ lsum,
              float* __restrict__ Og) {
    __shared__ float inv[128];
    __shared__ __align__(16) float Ol[64 * 132];
    const int t = threadIdx.x, p = blockIdx.x;
    const int b = p & 15, qblk = p >> 4;
    if (t < 128) {
        float l0 = lsum[p * 128 + t];
        float l1 = lsum[32768 + p * 128 + t];
        float l2 = lsum[65536 + p * 128 + t];
        inv[t] = 1.0f / (l0 + l1 + l2);
    }
    const uint2* P0 = (const uint2*)(part + (size_t)p * 16384);
    const uint2* P1 = (const uint2*)(part + (size_t)(256 + p) * 16384);
    const uint2* P2 = (const uint2*)(part + (size_t)(512 + p) * 16384);
    __syncthreads();
    #pragma unroll
    for (int h = 0; h < 2; ++h) {
        #pragma unroll
        for (int i = 0; i < 8; ++i) {
            int slot = i * 256 + t;
            int lc = slot >> 6, lane = slot & 63;
            int gc = h * 32 + lc;
            int s = (lc >> 3) & 1, dt = lc & 7;
            int qd = lane >> 4, c = lane & 15;
            int row = (lc >> 4) * 32 + s * 16 + c;
            int d0 = dt * 16 + qd * 4;
            size_t idx = (size_t)gc * 64 + lane;
            uint2 w0 = P0[idx], w1 = P1[idx], w2 = P2[idx];
            float iv = inv[h * 64 + row];
            float4 o;
            o.x = (bflo(w0.x) + bflo(w1.x) + bflo(w2.x)) * iv;
            o.y = (bfhi(w0.x) + bfhi(w1.x) + bfhi(w2.x)) * iv;
            o.z = (bflo(w0.y) + bflo(w1.y) + bflo(w2.y)) * iv;
            o.w = (bfhi(w0.y) + bfhi(w1.y) + bfhi(w2.y)) * iv;
            *(float4*)(&Ol[row * 132 + d0]) = o;
        }
        __syncthreads();
        #pragma unroll
        for (int i = 0; i < 8; ++i) {
            int slot = i * 256 + t;
            int row = slot >> 5, c4 = slot & 31;
            float4 val = *(const float4*)(&Ol[row * 132 + c4 * 4]);
            size_t q = (size_t)b * L_SEQ + qblk * 128 + h * 64 + row;
            *(float4*)(Og + q * D_HEAD + c4 * 4) = val;
        }
        __syncthreads();
    }
}

extern "C" void kernel_launch(void* const* d_in, const int* in_sizes, int n_in,
                              void* d_out, int out_size, void* d_ws, size_t ws_size,
                              hipStream_t stream) {
    const float* q = (const float*)d_in[0];
    const float* k = (const float*)d_in[1];
    const float* v = (const float*)d_in[2];
    float* out = (float*)d_out;
    u16* kb = (u16*)d_ws;
    u16* vt = (u16*)((char*)d_ws + TSZ);
    u16* part = (u16*)((char*)d_ws + W_PART);
    float* ls = (float*)((char*)d_ws + W_LSUM);
    prepass<<<dim3(1024), dim3(256), 0, stream>>>(k, v, kb, vt);
    attn3<<<dim3(768), dim3(256), 0, stream>>>(q, kb, vt, part, ls);
    combine3<<<dim3(256), dim3(256), 0, stream>>>(part, ls, out);
}